// Round 1
// baseline (100.647 us; speedup 1.0000x reference)
//
#include <hip/hip_runtime.h>

// Problem constants (B=2, C=32, H=W=64, P=3, D=7, K=4)
constexpr int NPIX = 2 * 64 * 64;   // 8192 pixels
constexpr float EPSF = 1e-12f;

// ---------------------------------------------------------------------------
// Kernel 2: wgt[pix][o] = wproj_b[o] + sum_i wproj_w[o*64+i] * cat[i][pix]
// cat = concat(feat_t, feat_tm1) channels at that pixel. 16 pixels per block
// share the weight reads; LDS transpose gives coalesced stores.
// ---------------------------------------------------------------------------
__global__ __launch_bounds__(256) void wgt_kernel(
    const float* __restrict__ feat_t, const float* __restrict__ feat_tm1,
    const float* __restrict__ wproj_w, const float* __restrict__ wproj_b,
    float* __restrict__ wgt_ws)
{
    __shared__ __align__(16) float catl[64 * 16];    // [i][px]
    __shared__ __align__(16) float wtile[16 * 289];  // [px][o] padded

    const int t = threadIdx.x;
    const int base = blockIdx.x * 16;       // 16 consecutive pixels, same row
    const int b  = base >> 12;
    const int y  = (base >> 6) & 63;
    const int x0 = base & 63;

    for (int idx = t; idx < 64 * 16; idx += 256) {
        int i = idx >> 4, px = idx & 15;
        const float* src = (i < 32) ? feat_t : feat_tm1;
        catl[idx] = src[((b * 32 + (i & 31)) << 12) + (y << 6) + x0 + px];
    }
    __syncthreads();

    const int px = t & 15, og = t >> 4;     // og in 0..15, 18 outputs each
    float acc[18];
    #pragma unroll
    for (int j = 0; j < 18; ++j) acc[j] = wproj_b[og * 18 + j];

    const float4* w4 = reinterpret_cast<const float4*>(wproj_w);
    for (int i = 0; i < 64; i += 4) {
        float c0 = catl[(i + 0) * 16 + px];
        float c1 = catl[(i + 1) * 16 + px];
        float c2 = catl[(i + 2) * 16 + px];
        float c3 = catl[(i + 3) * 16 + px];
        #pragma unroll
        for (int j = 0; j < 18; ++j) {
            float4 wv = w4[(og * 18 + j) * 16 + (i >> 2)];
            acc[j] += wv.x * c0 + wv.y * c1 + wv.z * c2 + wv.w * c3;
        }
    }
    #pragma unroll
    for (int j = 0; j < 18; ++j) wtile[px * 289 + og * 18 + j] = acc[j];
    __syncthreads();

    for (int idx = t; idx < 16 * 288; idx += 256) {
        int p = idx / 288, o = idx - p * 288;
        wgt_ws[(size_t)(base + p) * 288 + o] = wtile[p * 289 + o];
    }
}

// ---------------------------------------------------------------------------
// Main kernel: one wave per pixel, 4 waves (pixels) per block.
// ---------------------------------------------------------------------------
template <bool USE_WS>
__global__ __launch_bounds__(256) void agg_main(
    const float* __restrict__ feat_t, const float* __restrict__ feat_tm1,
    const float* __restrict__ agg_w, const float* __restrict__ agg_bp,
    const float* __restrict__ wproj_w, const float* __restrict__ wproj_b,
    const float* __restrict__ wgt_ws, float* __restrict__ out)
{
    __shared__ __align__(16) float tile[4][2592];  // [c][ty 0..8][tx 0..8]
    __shared__ __align__(16) float qbuf[4][384];   // [c][12] padded, normalized q; reused for partials
    __shared__ __align__(16) float catb[4][64];    // fallback path only

    const int lane = threadIdx.x & 63;
    const int wv   = threadIdx.x >> 6;
    const int pix  = blockIdx.x * 4 + wv;
    const int b = pix >> 12;
    const int y = (pix >> 6) & 63;
    const int x = pix & 63;
    float* tl = tile[wv];
    float* qb = qbuf[wv];

    const float* ftm1_b = feat_tm1 + ((size_t)b << 17);
    const float* ft_b   = feat_t   + ((size_t)b << 17);

    // --- stage feat_tm1 9x9x32 neighborhood (zero-padded at image border) ---
    for (int idx = lane; idx < 2592; idx += 64) {
        int c = idx / 81, r = idx - c * 81;
        int ty = r / 9,  tx = r - ty * 9;
        int gy = y - 4 + ty, gx = x - 4 + tx;
        float v = 0.f;
        if ((unsigned)gy < 64u && (unsigned)gx < 64u)
            v = ftm1_b[(c << 12) + (gy << 6) + gx];
        tl[idx] = v;
    }

    // --- stage query descriptor, normalize it in LDS ---
    float qv[5];
    float qp = 0.f;
    {
        int qn = 0;
        for (int idx = lane; idx < 288; idx += 64) {
            int c = idx / 9, p = idx - c * 9;
            int pi = p / 3, pj = p - pi * 3;
            int gy = y - 1 + pi, gx = x - 1 + pj;
            float v = 0.f;
            if ((unsigned)gy < 64u && (unsigned)gx < 64u)
                v = ft_b[(c << 12) + (gy << 6) + gx];
            qv[qn++] = v;
            qp += v * v;
        }
    }
    #pragma unroll
    for (int off = 32; off; off >>= 1) qp += __shfl_xor(qp, off, 64);
    const float qinv = 1.0f / fmaxf(sqrtf(qp), EPSF);
    {
        int qn = 0;
        for (int idx = lane; idx < 288; idx += 64) {
            int c = idx / 9, p = idx - c * 9;
            qb[c * 12 + p] = qv[qn++] * qinv;
        }
    }
    if constexpr (!USE_WS) {
        catb[wv][lane] = (lane < 32)
            ? ft_b[(lane << 12) + (y << 6) + x]
            : ftm1_b[((lane - 32) << 12) + (y << 6) + x];
    }
    __syncthreads();

    // --- similarity: lane d handles displacement d ---
    float sim;
    {
        const int d = lane;
        const int di = d / 7, dj = d - di * 7;
        const int cy = y + di - 3, cx = x + dj - 3;
        const bool act = d < 49;
        const bool valid = act && ((unsigned)cy < 64u) && ((unsigned)cx < 64u);
        sim = act ? 0.0f : -3.0e38f;   // OOB center: descriptor all-zero -> sim 0
        if (valid) {
            float dot = 0.f, n2 = 0.f;
            const int base = di * 9 + dj;
            for (int c = 0; c < 32; ++c) {
                const float4 qa = *reinterpret_cast<const float4*>(&qb[c * 12]);
                const float4 qd = *reinterpret_cast<const float4*>(&qb[c * 12 + 4]);
                const float  qe = qb[c * 12 + 8];
                const float* tp = &tl[c * 81 + base];
                float k0 = tp[0],  k1 = tp[1],  k2 = tp[2];
                float k3 = tp[9],  k4 = tp[10], k5 = tp[11];
                float k6 = tp[18], k7 = tp[19], k8 = tp[20];
                dot += qa.x*k0 + qa.y*k1 + qa.z*k2 + qa.w*k3
                     + qd.x*k4 + qd.y*k5 + qd.z*k6 + qd.w*k7 + qe*k8;
                n2  += k0*k0 + k1*k1 + k2*k2 + k3*k3 + k4*k4
                     + k5*k5 + k6*k6 + k7*k7 + k8*k8;
            }
            sim = dot / fmaxf(sqrtf(n2), EPSF);
        }
    }

    // --- top-4 (stable: ties -> lower displacement index, like lax.top_k) ---
    int chosen[4];
    {
        float s = sim; int si = lane;
        #pragma unroll
        for (int k = 0; k < 4; ++k) {
            float bs = s; int bi = si;
            #pragma unroll
            for (int off = 1; off < 64; off <<= 1) {
                float os = __shfl_xor(bs, off, 64);
                int   oi = __shfl_xor(bi, off, 64);
                if (os > bs || (os == bs && oi < bi)) { bs = os; bi = oi; }
            }
            chosen[k] = bi;             // identical on all lanes
            if (si == bi) s = -3.0e38f; // remove winner
        }
    }
    __syncthreads();   // qb is overwritten below; keep sim-phase reads ordered

    // --- gather top-4 descriptors, aggregate, multiply by wgt ---
    const float ab  = agg_bp[0];
    const float aw0 = agg_w[0], aw1 = agg_w[1], aw2 = agg_w[2], aw3 = agg_w[3];
    int  dbase[4];
    bool dvalid[4];
    #pragma unroll
    for (int k = 0; k < 4; ++k) {
        int dk = chosen[k];
        int di = dk / 7, dj = dk - di * 7;
        int cy = y + di - 3, cx = x + dj - 3;
        dvalid[k] = ((unsigned)cy < 64u) && ((unsigned)cx < 64u);
        dbase[k]  = di * 9 + dj;
    }
    for (int o = lane; o < 288; o += 64) {
        int c = o / 9, p = o - c * 9;
        int pi = p / 3, pj = p - pi * 3;
        int off = c * 81 + pi * 9 + pj;
        float v0 = dvalid[0] ? tl[off + dbase[0]] : 0.f;
        float v1 = dvalid[1] ? tl[off + dbase[1]] : 0.f;
        float v2 = dvalid[2] ? tl[off + dbase[2]] : 0.f;
        float v3 = dvalid[3] ? tl[off + dbase[3]] : 0.f;
        float a = ab + aw0 * v0 + aw1 * v1 + aw2 * v2 + aw3 * v3;
        float wg;
        if constexpr (USE_WS) {
            wg = wgt_ws[(size_t)pix * 288 + o];
        } else {
            wg = wproj_b[o];
            const float4* w4  = reinterpret_cast<const float4*>(wproj_w);
            const float4* cb4 = reinterpret_cast<const float4*>(&catb[wv][0]);
            #pragma unroll
            for (int i4 = 0; i4 < 16; ++i4) {
                float4 wv4 = w4[o * 16 + i4];
                float4 cv  = cb4[i4];
                wg += wv4.x*cv.x + wv4.y*cv.y + wv4.z*cv.z + wv4.w*cv.w;
            }
        }
        qb[c * 12 + p] = a * wg;   // reuse q storage for partial products
    }
    __syncthreads();

    if (lane < 32) {
        const float* qq = &qb[lane * 12];
        float sum = (((qq[0]+qq[1]) + (qq[2]+qq[3])) + ((qq[4]+qq[5]) + (qq[6]+qq[7]))) + qq[8];
        out[((size_t)b << 17) + (lane << 12) + (y << 6) + x] = sum;
    }
}

// ---------------------------------------------------------------------------
extern "C" void kernel_launch(void* const* d_in, const int* in_sizes, int n_in,
                              void* d_out, int out_size, void* d_ws, size_t ws_size,
                              hipStream_t stream)
{
    const float* feat_t   = (const float*)d_in[0];
    const float* feat_tm1 = (const float*)d_in[1];
    const float* agg_w    = (const float*)d_in[2];
    const float* agg_b    = (const float*)d_in[3];
    const float* wproj_w  = (const float*)d_in[4];
    const float* wproj_b  = (const float*)d_in[5];
    float* outp = (float*)d_out;

    const size_t need = (size_t)NPIX * 288 * sizeof(float);
    if (ws_size >= need) {
        float* wgt = (float*)d_ws;
        wgt_kernel<<<NPIX / 16, 256, 0, stream>>>(feat_t, feat_tm1, wproj_w, wproj_b, wgt);
        agg_main<true><<<NPIX / 4, 256, 0, stream>>>(feat_t, feat_tm1, agg_w, agg_b,
                                                     wproj_w, wproj_b, wgt, outp);
    } else {
        agg_main<false><<<NPIX / 4, 256, 0, stream>>>(feat_t, feat_tm1, agg_w, agg_b,
                                                      wproj_w, wproj_b, nullptr, outp);
    }
}

// Round 2
// 60.136 us; speedup vs baseline: 1.6737x; 1.6737x over previous
//
#include <hip/hip_runtime.h>

// Problem constants (B=2, C=32, H=W=64, P=3, D=7, K=4)
constexpr int NPIX = 2 * 64 * 64;   // 8192 pixels
constexpr float EPSF = 1e-12f;

// ---------------------------------------------------------------------------
// wgt kernel: wgt[pix][o] = wproj_b[o] + sum_i wproj_w[o*64+i] * cat[i][pix]
// ---------------------------------------------------------------------------
__global__ __launch_bounds__(256) void wgt_kernel(
    const float* __restrict__ feat_t, const float* __restrict__ feat_tm1,
    const float* __restrict__ wproj_w, const float* __restrict__ wproj_b,
    float* __restrict__ wgt_ws)
{
    __shared__ __align__(16) float catl[64 * 16];    // [i][px]
    __shared__ __align__(16) float wtile[16 * 289];  // [px][o] padded

    const int t = threadIdx.x;
    const int base = blockIdx.x * 16;       // 16 consecutive pixels, same row
    const int b  = base >> 12;
    const int y  = (base >> 6) & 63;
    const int x0 = base & 63;

    for (int idx = t; idx < 64 * 16; idx += 256) {
        int i = idx >> 4, px = idx & 15;
        const float* src = (i < 32) ? feat_t : feat_tm1;
        catl[idx] = src[((b * 32 + (i & 31)) << 12) + (y << 6) + x0 + px];
    }
    __syncthreads();

    const int px = t & 15, og = t >> 4;     // og in 0..15, 18 outputs each
    float acc[18];
    #pragma unroll
    for (int j = 0; j < 18; ++j) acc[j] = wproj_b[og * 18 + j];

    const float4* w4 = reinterpret_cast<const float4*>(wproj_w);
    for (int i = 0; i < 64; i += 4) {
        float c0 = catl[(i + 0) * 16 + px];
        float c1 = catl[(i + 1) * 16 + px];
        float c2 = catl[(i + 2) * 16 + px];
        float c3 = catl[(i + 3) * 16 + px];
        #pragma unroll
        for (int j = 0; j < 18; ++j) {
            float4 wv = w4[(og * 18 + j) * 16 + (i >> 2)];
            acc[j] += wv.x * c0 + wv.y * c1 + wv.z * c2 + wv.w * c3;
        }
    }
    #pragma unroll
    for (int j = 0; j < 18; ++j) wtile[px * 289 + og * 18 + j] = acc[j];
    __syncthreads();

    for (int idx = t; idx < 16 * 288; idx += 256) {
        int p = idx / 288, o = idx - p * 288;
        wgt_ws[(size_t)(base + p) * 288 + o] = wtile[p * 289 + o];
    }
}

// ---------------------------------------------------------------------------
// K1 prep: rBM(y,x) = 1/max(sqrt(box3x3 of sum_c ft^2), eps)
//          rBN(y,x) = same for ftm1; also ftm1_t[b][y][x][c] transposed copy.
// Block: 2-row band (+1 halo each side), grid (32, 2).
// ---------------------------------------------------------------------------
__global__ __launch_bounds__(256) void prep_kernel(
    const float* __restrict__ ft, const float* __restrict__ ftm1,
    float* __restrict__ ftm1_t, float* __restrict__ rBM, float* __restrict__ rBN)
{
    __shared__ float mbuf[4][66];
    __shared__ float nbuf[4][66];
    const int t = threadIdx.x;
    const int r = t >> 6;            // 0..3 (rows y0-1 .. y0+2)
    const int x = t & 63;
    const int b = blockIdx.y;
    const int y0 = blockIdx.x * 2;
    const int a = y0 - 1 + r;
    const float* ftb = ft + ((size_t)b << 17);
    const float* f1b = ftm1 + ((size_t)b << 17);

    float m = 0.f, n = 0.f;
    if ((unsigned)a < 64u) {
        const int off = (a << 6) + x;
        float4* tdst = reinterpret_cast<float4*>(ftm1_t) + (size_t)((b << 12) + off) * 8;
        #pragma unroll
        for (int c4 = 0; c4 < 8; ++c4) {
            float4 q; float va, vb;
            va = ftb[(((c4 * 4 + 0)) << 12) + off]; vb = f1b[(((c4 * 4 + 0)) << 12) + off];
            m += va * va; n += vb * vb; q.x = vb;
            va = ftb[(((c4 * 4 + 1)) << 12) + off]; vb = f1b[(((c4 * 4 + 1)) << 12) + off];
            m += va * va; n += vb * vb; q.y = vb;
            va = ftb[(((c4 * 4 + 2)) << 12) + off]; vb = f1b[(((c4 * 4 + 2)) << 12) + off];
            m += va * va; n += vb * vb; q.z = vb;
            va = ftb[(((c4 * 4 + 3)) << 12) + off]; vb = f1b[(((c4 * 4 + 3)) << 12) + off];
            m += va * va; n += vb * vb; q.w = vb;
            tdst[c4] = q;
        }
    }
    if (x == 0)  { mbuf[r][0]  = 0.f; nbuf[r][0]  = 0.f; }
    if (x == 63) { mbuf[r][65] = 0.f; nbuf[r][65] = 0.f; }
    mbuf[r][x + 1] = m;
    nbuf[r][x + 1] = n;
    __syncthreads();

    if (r == 1 || r == 2) {
        const int y = y0 + r - 1;
        float bm = 0.f, bn = 0.f;
        #pragma unroll
        for (int i = 0; i < 3; ++i)
            #pragma unroll
            for (int j = 0; j < 3; ++j) {
                bm += mbuf[r - 1 + i][x + j];
                bn += nbuf[r - 1 + i][x + j];
            }
        const int o = (b << 12) + (y << 6) + x;
        rBM[o] = 1.0f / fmaxf(sqrtf(bm), EPSF);
        rBN[o] = 1.0f / fmaxf(sqrtf(bn), EPSF);
    }
}

// ---------------------------------------------------------------------------
// K2 sim: for one (b, uv, 16-row band): S rows -> 3x3 box-sum -> sim.
// sim(y,x,uv) = boxsum(S) * rBM(y,x) * rBN(cy,cx), 0 if center OOB.
// Writes sim_ws[pix*64 + uv].
// ---------------------------------------------------------------------------
__global__ __launch_bounds__(256) void sim_kernel(
    const float* __restrict__ ft, const float* __restrict__ ftm1,
    const float* __restrict__ rBM, const float* __restrict__ rBN,
    float* __restrict__ simb)
{
    __shared__ float sbuf[18][64];
    const int uv = blockIdx.x;       // 0..48
    const int band = blockIdx.y;     // 0..3
    const int b = blockIdx.z;
    const int u = uv / 7 - 3;
    const int v = uv % 7 - 3;
    const int y0 = band << 4;
    const int lane = threadIdx.x & 63;
    const int wv = threadIdx.x >> 6;
    const float* ftb = ft + ((size_t)b << 17);
    const float* f1b = ftm1 + ((size_t)b << 17);

    // S(a, x) = sum_c ft[c,a,x] * ftm1[c,a+u,x+v]; zero if any position OOB
    for (int r = wv; r < 18; r += 4) {
        const int a = y0 - 1 + r;
        const int brow = a + u;
        const int bcol = lane + v;
        float s = 0.f;
        if ((unsigned)a < 64u && (unsigned)brow < 64u && (unsigned)bcol < 64u) {
            const int aoff = (a << 6) + lane;
            const int boff = (brow << 6) + bcol;
            #pragma unroll 8
            for (int c = 0; c < 32; ++c)
                s += ftb[(c << 12) + aoff] * f1b[(c << 12) + boff];
        }
        sbuf[r][lane] = s;
    }
    __syncthreads();

    for (int yl = threadIdx.x >> 6; yl < 16; yl += 4) {
        const int y = y0 + yl;
        const int x = lane;
        const int cy = y + u, cx = x + v;
        float sim = 0.f;
        if ((unsigned)cy < 64u && (unsigned)cx < 64u) {
            float dot = 0.f;
            #pragma unroll
            for (int i = 0; i < 3; ++i) {
                float rs = sbuf[yl + i][x];
                if (x > 0)  rs += sbuf[yl + i][x - 1];
                if (x < 63) rs += sbuf[yl + i][x + 1];
                dot += rs;
            }
            sim = dot * rBM[(b << 12) + (y << 6) + x]
                      * rBN[(b << 12) + (cy << 6) + cx];
        }
        simb[(size_t)(((b << 12) + (y << 6) + x) << 6) + uv] = sim;
    }
}

// ---------------------------------------------------------------------------
// K3: top-4 per pixel + gather (via transposed ftm1) + aggregate + output.
// Half-wave (32 lanes = 32 channels) per pixel; block = 8 pixels (same row).
// ---------------------------------------------------------------------------
__global__ __launch_bounds__(256) void gather_kernel(
    const float* __restrict__ ftm1_t, const float* __restrict__ simb,
    const float* __restrict__ wgt, const float* __restrict__ agg_w,
    const float* __restrict__ agg_bp, float* __restrict__ out)
{
    __shared__ float obuf[4][64];
    const int lane = threadIdx.x & 63;
    const int wv = threadIdx.x >> 6;
    const int half = lane >> 5;
    const int c = lane & 31;
    const int pix0 = blockIdx.x << 3;
    const int pix = pix0 + (wv << 1) + half;
    const int b = pix >> 12, y = (pix >> 6) & 63, x = pix & 63;

    // ---- top-4 over the 49 sims (stable: ties -> lower uv) ----
    const float* sp = simb + ((size_t)pix << 6);
    float s0 = sp[c];
    float s1 = (c + 32 < 49) ? sp[c + 32] : -3.0e38f;
    int chosen[4];
    #pragma unroll
    for (int k = 0; k < 4; ++k) {
        float bs; int bi;
        if (s0 >= s1) { bs = s0; bi = c; }
        else          { bs = s1; bi = c + 32; }
        #pragma unroll
        for (int off = 16; off; off >>= 1) {   // stays within the half-wave
            float os = __shfl_xor(bs, off, 64);
            int   oi = __shfl_xor(bi, off, 64);
            if (os > bs || (os == bs && oi < bi)) { bs = os; bi = oi; }
        }
        chosen[k] = bi;
        if (bi == c)           s0 = -3.0e38f;
        else if (bi == c + 32) s1 = -3.0e38f;
    }

    // ---- gather + aggregate ----
    float aw[4];
    aw[0] = agg_w[0]; aw[1] = agg_w[1]; aw[2] = agg_w[2]; aw[3] = agg_w[3];
    const float ab = agg_bp[0];

    int cyv[4], cxv[4]; bool cval[4];
    #pragma unroll
    for (int k = 0; k < 4; ++k) {
        int d = chosen[k];
        int di = d / 7, dj = d - di * 7;
        int cy = y + di - 3, cx = x + dj - 3;
        cval[k] = ((unsigned)cy < 64u) && ((unsigned)cx < 64u);
        cyv[k] = cy; cxv[k] = cx;
    }

    float outc = 0.f;
    const float* wp = wgt + (size_t)pix * 288 + c * 9;
    #pragma unroll
    for (int pi = 0; pi < 3; ++pi) {
        #pragma unroll
        for (int pj = 0; pj < 3; ++pj) {
            float g = ab;
            #pragma unroll
            for (int k = 0; k < 4; ++k) {
                int row = cyv[k] + pi - 1, col = cxv[k] + pj - 1;
                float vv = 0.f;
                if (cval[k] && (unsigned)row < 64u && (unsigned)col < 64u)
                    vv = ftm1_t[((size_t)((b << 12) + (row << 6) + col) << 5) + c];
                g += aw[k] * vv;
            }
            outc += wp[pi * 3 + pj] * g;
        }
    }
    obuf[wv][lane] = outc;
    __syncthreads();

    {
        const int cc = threadIdx.x >> 3;   // 0..31
        const int px = threadIdx.x & 7;    // 0..7
        const float vv = obuf[px >> 1][((px & 1) << 5) + cc];
        const int bb = pix0 >> 12, yy = (pix0 >> 6) & 63, xx0 = pix0 & 63;
        out[((size_t)((bb << 5) + cc) << 12) + (yy << 6) + xx0 + px] = vv;
    }
}

// ---------------------------------------------------------------------------
// Fallback (no workspace): round-1 monolithic wave-per-pixel kernel.
// ---------------------------------------------------------------------------
__global__ __launch_bounds__(256) void agg_fallback(
    const float* __restrict__ feat_t, const float* __restrict__ feat_tm1,
    const float* __restrict__ agg_w, const float* __restrict__ agg_bp,
    const float* __restrict__ wproj_w, const float* __restrict__ wproj_b,
    float* __restrict__ out)
{
    __shared__ __align__(16) float tile[4][2592];
    __shared__ __align__(16) float qbuf[4][384];
    __shared__ __align__(16) float catb[4][64];

    const int lane = threadIdx.x & 63;
    const int wv   = threadIdx.x >> 6;
    const int pix  = blockIdx.x * 4 + wv;
    const int b = pix >> 12;
    const int y = (pix >> 6) & 63;
    const int x = pix & 63;
    float* tl = tile[wv];
    float* qb = qbuf[wv];

    const float* ftm1_b = feat_tm1 + ((size_t)b << 17);
    const float* ft_b   = feat_t   + ((size_t)b << 17);

    for (int idx = lane; idx < 2592; idx += 64) {
        int c = idx / 81, r = idx - c * 81;
        int ty = r / 9,  tx = r - ty * 9;
        int gy = y - 4 + ty, gx = x - 4 + tx;
        float v = 0.f;
        if ((unsigned)gy < 64u && (unsigned)gx < 64u)
            v = ftm1_b[(c << 12) + (gy << 6) + gx];
        tl[idx] = v;
    }

    float qv[5];
    float qp = 0.f;
    {
        int qn = 0;
        for (int idx = lane; idx < 288; idx += 64) {
            int c = idx / 9, p = idx - c * 9;
            int pi = p / 3, pj = p - pi * 3;
            int gy = y - 1 + pi, gx = x - 1 + pj;
            float v = 0.f;
            if ((unsigned)gy < 64u && (unsigned)gx < 64u)
                v = ft_b[(c << 12) + (gy << 6) + gx];
            qv[qn++] = v;
            qp += v * v;
        }
    }
    #pragma unroll
    for (int off = 32; off; off >>= 1) qp += __shfl_xor(qp, off, 64);
    const float qinv = 1.0f / fmaxf(sqrtf(qp), EPSF);
    {
        int qn = 0;
        for (int idx = lane; idx < 288; idx += 64) {
            int c = idx / 9, p = idx - c * 9;
            qb[c * 12 + p] = qv[qn++] * qinv;
        }
    }
    catb[wv][lane] = (lane < 32)
        ? ft_b[(lane << 12) + (y << 6) + x]
        : ftm1_b[((lane - 32) << 12) + (y << 6) + x];
    __syncthreads();

    float sim;
    {
        const int d = lane;
        const int di = d / 7, dj = d - di * 7;
        const int cy = y + di - 3, cx = x + dj - 3;
        const bool act = d < 49;
        const bool valid = act && ((unsigned)cy < 64u) && ((unsigned)cx < 64u);
        sim = act ? 0.0f : -3.0e38f;
        if (valid) {
            float dot = 0.f, n2 = 0.f;
            const int base = di * 9 + dj;
            for (int c = 0; c < 32; ++c) {
                const float4 qa = *reinterpret_cast<const float4*>(&qb[c * 12]);
                const float4 qd = *reinterpret_cast<const float4*>(&qb[c * 12 + 4]);
                const float  qe = qb[c * 12 + 8];
                const float* tp = &tl[c * 81 + base];
                float k0 = tp[0],  k1 = tp[1],  k2 = tp[2];
                float k3 = tp[9],  k4 = tp[10], k5 = tp[11];
                float k6 = tp[18], k7 = tp[19], k8 = tp[20];
                dot += qa.x*k0 + qa.y*k1 + qa.z*k2 + qa.w*k3
                     + qd.x*k4 + qd.y*k5 + qd.z*k6 + qd.w*k7 + qe*k8;
                n2  += k0*k0 + k1*k1 + k2*k2 + k3*k3 + k4*k4
                     + k5*k5 + k6*k6 + k7*k7 + k8*k8;
            }
            sim = dot / fmaxf(sqrtf(n2), EPSF);
        }
    }

    int chosen[4];
    {
        float s = sim; int si = lane;
        #pragma unroll
        for (int k = 0; k < 4; ++k) {
            float bs = s; int bi = si;
            #pragma unroll
            for (int off = 1; off < 64; off <<= 1) {
                float os = __shfl_xor(bs, off, 64);
                int   oi = __shfl_xor(bi, off, 64);
                if (os > bs || (os == bs && oi < bi)) { bs = os; bi = oi; }
            }
            chosen[k] = bi;
            if (si == bi) s = -3.0e38f;
        }
    }
    __syncthreads();

    const float ab  = agg_bp[0];
    const float aw0 = agg_w[0], aw1 = agg_w[1], aw2 = agg_w[2], aw3 = agg_w[3];
    int  dbase[4];
    bool dvalid[4];
    #pragma unroll
    for (int k = 0; k < 4; ++k) {
        int dk = chosen[k];
        int di = dk / 7, dj = dk - di * 7;
        int cy = y + di - 3, cx = x + dj - 3;
        dvalid[k] = ((unsigned)cy < 64u) && ((unsigned)cx < 64u);
        dbase[k]  = di * 9 + dj;
    }
    for (int o = lane; o < 288; o += 64) {
        int c = o / 9, p = o - c * 9;
        int pi = p / 3, pj = p - pi * 3;
        int off = c * 81 + pi * 9 + pj;
        float v0 = dvalid[0] ? tl[off + dbase[0]] : 0.f;
        float v1 = dvalid[1] ? tl[off + dbase[1]] : 0.f;
        float v2 = dvalid[2] ? tl[off + dbase[2]] : 0.f;
        float v3 = dvalid[3] ? tl[off + dbase[3]] : 0.f;
        float a = ab + aw0 * v0 + aw1 * v1 + aw2 * v2 + aw3 * v3;
        float wg = wproj_b[o];
        const float4* w4  = reinterpret_cast<const float4*>(wproj_w);
        const float4* cb4 = reinterpret_cast<const float4*>(&catb[wv][0]);
        #pragma unroll
        for (int i4 = 0; i4 < 16; ++i4) {
            float4 wv4 = w4[o * 16 + i4];
            float4 cv  = cb4[i4];
            wg += wv4.x*cv.x + wv4.y*cv.y + wv4.z*cv.z + wv4.w*cv.w;
        }
        qb[c * 12 + p] = a * wg;
    }
    __syncthreads();

    if (lane < 32) {
        const float* qq = &qb[lane * 12];
        float sum = (((qq[0]+qq[1]) + (qq[2]+qq[3])) + ((qq[4]+qq[5]) + (qq[6]+qq[7]))) + qq[8];
        out[((size_t)b << 17) + (lane << 12) + (y << 6) + x] = sum;
    }
}

// ---------------------------------------------------------------------------
extern "C" void kernel_launch(void* const* d_in, const int* in_sizes, int n_in,
                              void* d_out, int out_size, void* d_ws, size_t ws_size,
                              hipStream_t stream)
{
    const float* feat_t   = (const float*)d_in[0];
    const float* feat_tm1 = (const float*)d_in[1];
    const float* agg_w    = (const float*)d_in[2];
    const float* agg_b    = (const float*)d_in[3];
    const float* wproj_w  = (const float*)d_in[4];
    const float* wproj_b  = (const float*)d_in[5];
    float* outp = (float*)d_out;

    // ws layout (floats):
    //   wgt    : [0,               2359296)   8192*288
    //   sim    : [2359296,         2883584)   8192*64
    //   ftm1_t : [2883584,         3145728)   8192*32
    //   rBM    : [3145728,         3153920)   8192
    //   rBN    : [3153920,         3162112)   8192
    const size_t need = (size_t)3162112 * sizeof(float);
    if (ws_size >= need) {
        float* ws     = (float*)d_ws;
        float* wgt    = ws;
        float* simb   = ws + 2359296;
        float* ftm1_t = ws + 2883584;
        float* rBM    = ws + 3145728;
        float* rBN    = ws + 3153920;

        prep_kernel<<<dim3(32, 2), 256, 0, stream>>>(feat_t, feat_tm1, ftm1_t, rBM, rBN);
        wgt_kernel<<<NPIX / 16, 256, 0, stream>>>(feat_t, feat_tm1, wproj_w, wproj_b, wgt);
        sim_kernel<<<dim3(49, 4, 2), 256, 0, stream>>>(feat_t, feat_tm1, rBM, rBN, simb);
        gather_kernel<<<NPIX / 8, 256, 0, stream>>>(ftm1_t, simb, wgt, agg_w, agg_b, outp);
    } else {
        agg_fallback<<<NPIX / 4, 256, 0, stream>>>(feat_t, feat_tm1, agg_w, agg_b,
                                                   wproj_w, wproj_b, outp);
    }
}